// Round 9
// baseline (455.362 us; speedup 1.0000x reference)
//
#include <hip/hip_runtime.h>
#include <math.h>

#define PB 8
#define PL 1024
#define PC 1024
#define PH 16
#define PD 64
#define MAX_SCALE_MUL 4.605170185988092f  // log(100)
#define LOG2E 1.4426950408889634f

typedef __attribute__((ext_vector_type(8))) short s16x8;
typedef __attribute__((ext_vector_type(4))) float f32x4;

#define MFMA16(a, b, c) __builtin_amdgcn_mfma_f32_16x16x32_bf16(a, b, c, 0, 0, 0)

#if __has_builtin(__builtin_amdgcn_exp2f)
#define EXP2(x) __builtin_amdgcn_exp2f(x)
#else
#define EXP2(x) exp2f(x)
#endif

// fp32 -> bf16 round-to-nearest-even (scalar fallback path)
__device__ __forceinline__ unsigned short f2bf(float f) {
    unsigned u = __float_as_uint(f);
    unsigned r = (u + 0x7fffu + ((u >> 16) & 1u)) >> 16;
    return (unsigned short)r;
}

// packed pair fp32x2 -> bf16x2 (low = a, high = b)
__device__ __forceinline__ unsigned pk2bf(float a, float b) {
#if __has_builtin(__builtin_amdgcn_cvt_pk_bf16_f32)
    typedef __attribute__((ext_vector_type(2))) __bf16 bf16x2_t;
    bf16x2_t r = __builtin_amdgcn_cvt_pk_bf16_f32(a, b);
    return __builtin_bit_cast(unsigned, r);
#else
    return (unsigned)f2bf(a) | ((unsigned)f2bf(b) << 16);
#endif
}

// async global->LDS, 16 bytes per lane; lptr must be wave-uniform
__device__ __forceinline__ void gl2lds16(const void* g, void* l) {
    __builtin_amdgcn_global_load_lds(
        (const __attribute__((address_space(1))) unsigned int*)g,
        (__attribute__((address_space(3))) unsigned int*)l, 16, 0, 0);
}

// ---------------------------------------------------------------------------
// bias nonzero scan: 256 blocks x 256 threads x 4 float4 = 1M floats
// ---------------------------------------------------------------------------
__global__ __launch_bounds__(256) void bias_flag_kernel(
    const float* __restrict__ bias, int* __restrict__ flag)
{
    int idx = blockIdx.x * 256 + threadIdx.x;
    const float4* b4 = (const float4*)bias;
    bool nz = false;
#pragma unroll
    for (int i = 0; i < 4; i++) {
        float4 v = b4[idx * 4 + i];
        nz |= (v.x != 0.f) | (v.y != 0.f) | (v.z != 0.f) | (v.w != 0.f);
    }
    if (nz) atomicOr(flag, 1);
}

// ---------------------------------------------------------------------------
// cast fp32 -> bf16 for x, W_qkv, W_proj in one launch.
// ---------------------------------------------------------------------------
__global__ __launch_bounds__(256) void cast3_kernel(
    const float* __restrict__ a, const float* __restrict__ b,
    const float* __restrict__ c,
    unsigned short* __restrict__ oa, unsigned short* __restrict__ ob,
    unsigned short* __restrict__ oc)
{
    int blk = blockIdx.x;
    const float* src; unsigned short* dst; int base;
    if (blk < 8192)       { src = a; dst = oa; base = blk; }
    else if (blk < 11264) { src = b; dst = ob; base = blk - 8192; }
    else                  { src = c; dst = oc; base = blk - 11264; }
    int i = base * 256 + threadIdx.x;
    float4 v = ((const float4*)src)[i];
    ((uint2*)dst)[i] = make_uint2(pk2bf(v.x, v.y), pk2bf(v.z, v.w));
}

// ---------------------------------------------------------------------------
// Kernel 1: LEAN QKV GEMM (bf16 MFMA), TRANSPOSED compute: C^T = W . X^T.
// A-operand = W rows (n/d dim), B-operand = X rows (m/l dim), so C/D has
// d in quad*4+reg (contiguous per lane) and l in rr. Epilogue is 16 packed
// 8-byte stores per lane instead of 64 scattered 2-byte stores (R8 lesson).
// ---------------------------------------------------------------------------
__global__ __launch_bounds__(256) void gemm_qkv_lean(
    const unsigned short* __restrict__ Xh,
    const unsigned short* __restrict__ Wh,
    const float* __restrict__ qb, const float* __restrict__ vb,
    unsigned short* __restrict__ Qh, unsigned short* __restrict__ Kh,
    unsigned short* __restrict__ Vh)
{
    __shared__ unsigned short As[128 * 32];
    __shared__ unsigned short Bs[128 * 32];
    const int tid  = threadIdx.x;
    const int wave = tid >> 6, lane = tid & 63;
    const int wm = wave & 1, wn = wave >> 1;
    const int quad = lane >> 4, rr = lane & 15;
    const int m0 = blockIdx.x * 128, n0 = blockIdx.y * 128;

    f32x4 acc[4][4];   // acc[i][j]: i over n(d) sub-tiles, j over m(l) sub-tiles
#pragma unroll
    for (int i = 0; i < 4; i++)
#pragma unroll
        for (int j = 0; j < 4; j++) acc[i][j] = (f32x4){0.f, 0.f, 0.f, 0.f};

    const int rw = lane >> 2;
    const int cc = lane & 3;
    const int g  = cc ^ ((rw >> 1) & 3);
    const int srow = wave * 32 + rw;
    const unsigned short* gA0 = Xh + (size_t)(m0 + srow) * 1024 + g * 8;
    const unsigned short* gA1 = gA0 + (size_t)16 * 1024;
    const unsigned short* gB0 = Wh + (size_t)(n0 + srow) * 1024 + g * 8;
    const unsigned short* gB1 = gB0 + (size_t)16 * 1024;
    unsigned short* lA0 = &As[(wave * 32) * 32];
    unsigned short* lA1 = &As[(wave * 32 + 16) * 32];
    unsigned short* lB0 = &Bs[(wave * 32) * 32];
    unsigned short* lB1 = &Bs[(wave * 32 + 16) * 32];

    const int swz = (rr >> 1) & 3;
    const int coff = ((quad ^ swz) * 8);

    for (int k0 = 0; k0 < 1024; k0 += 32) {
        gl2lds16(gA0, lA0); gl2lds16(gA1, lA1);
        gl2lds16(gB0, lB0); gl2lds16(gB1, lB1);
        gA0 += 32; gA1 += 32; gB0 += 32; gB1 += 32;
        __syncthreads();

        s16x8 wf[4], xf[4];
#pragma unroll
        for (int i = 0; i < 4; i++)
            wf[i] = *(const s16x8*)&Bs[(wn * 64 + i * 16 + rr) * 32 + coff];
#pragma unroll
        for (int j = 0; j < 4; j++)
            xf[j] = *(const s16x8*)&As[(wm * 64 + j * 16 + rr) * 32 + coff];
#pragma unroll
        for (int i = 0; i < 4; i++)
#pragma unroll
            for (int j = 0; j < 4; j++)
                acc[i][j] = MFMA16(wf[i], xf[j], acc[i][j]);
        __syncthreads();
    }

    // epilogue: d = wn*64 + i*16 + quad*4 + reg (contiguous per lane),
    //           l = lb0 + j*16 + rr.  Packed 8B stores.
    const int b     = m0 >> 10;
    const int which = n0 >> 10;                       // 0=Q 1=K 2=V (uniform)
    const int h     = ((n0 & 1023) + wn * 64) >> 6;   // head (uniform per wave)
    const int lb0   = (m0 & 1023) + wm * 64;
    unsigned short* dst = (which == 0) ? Qh : ((which == 1) ? Kh : Vh);
    unsigned short* base = dst + ((size_t)(b * PH + h) * PL) * PD;
    const float* bvec = (which == 0) ? qb : vb;

#pragma unroll
    for (int i = 0; i < 4; i++) {
        const int d0 = i * 16 + quad * 4;             // within-head d, +reg
        float4 b4 = make_float4(0.f, 0.f, 0.f, 0.f);
        if (which != 1) b4 = *(const float4*)(bvec + h * 64 + d0);
#pragma unroll
        for (int j = 0; j < 4; j++) {
            const int l = lb0 + j * 16 + rr;
            uint2 pk = make_uint2(
                pk2bf(acc[i][j][0] + b4.x, acc[i][j][1] + b4.y),
                pk2bf(acc[i][j][2] + b4.z, acc[i][j][3] + b4.w));
            *(uint2*)(base + (size_t)l * PD + d0) = pk;
        }
    }
}

// ---------------------------------------------------------------------------
// Kernel 2: fused postprocess (3 roles by block range).
//  [0,16384):      Q norm + *exp(min(sml,MAX))*log2e + RoPE, in place (bf16)
//  [16384,32768):  K norm + RoPE, in place (bf16)
//  [32768,34816):  V transpose (B,H,L,D) -> (B,H,D,L)
// ---------------------------------------------------------------------------
__global__ __launch_bounds__(256) void postproc_kernel(
    unsigned short* __restrict__ Qh, unsigned short* __restrict__ Kh,
    const unsigned short* __restrict__ Vh, unsigned short* __restrict__ Vt,
    const float* __restrict__ freqs, const float* __restrict__ sml)
{
    const int blk = blockIdx.x;
    const int tid = threadIdx.x;

    if (blk < 32768) {
        const bool isQ = blk < 16384;
        const int rb = isQ ? blk : blk - 16384;
        const int row = rb * 8 + (tid >> 5);       // 8 rows per block
        const int li  = tid & 31;                  // pair index within row
        const int h = (row >> 10) & (PH - 1);
        const int l = row & (PL - 1);

        unsigned short* buf = isQ ? Qh : Kh;
        unsigned* p = (unsigned*)(buf + (size_t)row * PD) + li;
        unsigned v = *p;
        float v0 = __uint_as_float(v << 16);
        float v1 = __uint_as_float(v & 0xffff0000u);

        float ss = fmaf(v0, v0, v1 * v1);
#pragma unroll
        for (int off = 1; off <= 16; off <<= 1) ss += __shfl_xor(ss, off);

        float smul = isQ ? (__expf(fminf(sml[h], MAX_SCALE_MUL)) * LOG2E) : 1.0f;
        float scale = smul / fmaxf(sqrtf(ss), 1e-12f);
        v0 *= scale; v1 *= scale;

        float2 cs = ((const float2*)freqs)[l * 32 + li];
        float re = v0 * cs.x - v1 * cs.y;
        float im = fmaf(v0, cs.y, v1 * cs.x);
        *p = pk2bf(re, im);
        return;
    }

    // V transpose
    const int vblk = blk - 32768;
    const int bh = vblk >> 4;
    const int l0 = (vblk & 15) * 64;
#pragma unroll
    for (int s = 0; s < 2; s++) {
        int slot = s * 256 + tid;
        int d  = slot & 63;
        int lb = l0 + (slot >> 6) * 8;
        unsigned o[4];
#pragma unroll
        for (int i = 0; i < 4; i++) {
            unsigned short a0 = Vh[((size_t)bh * PL + lb + 2 * i) * PD + d];
            unsigned short a1 = Vh[((size_t)bh * PL + lb + 2 * i + 1) * PD + d];
            o[i] = (unsigned)a0 | ((unsigned)a1 << 16);
        }
        *(uint4*)&Vt[((size_t)bh * PD + d) * PL + lb] = make_uint4(o[0], o[1], o[2], o[3]);
    }
}

// ---------------------------------------------------------------------------
// Kernel 3: flash attention, ZERO-BARRIER K-loop. K and V^T fragments are
// loaded directly from global (L1/L2-served; per-CU tile working set 16 KB
// fits L1) -- no LDS staging, no __syncthreads anywhere. Only the wave-
// private P^T repack uses LDS (9.2 KB/block). Static-bound softmax with -M
// folded into MFMA C-init. q-tile 64 keeps VGPR ~90 -> 5 waves/SIMD.
// grid = (bh, qtile): same-bh blocks are 128 apart (== 0 mod 8) -> same XCD.
// ---------------------------------------------------------------------------
__global__ __launch_bounds__(256) void attn_mfma(
    const unsigned short* __restrict__ Qh, const unsigned short* __restrict__ Kh,
    const unsigned short* __restrict__ Vt, const float* __restrict__ bias,
    const float* __restrict__ sml, const int* __restrict__ biasflag,
    unsigned short* __restrict__ O)
{
    __shared__ unsigned int Ps[4][16 * 36];   // per-wave P^T pairs, stride 36

    const int tid  = threadIdx.x;
    const int wave = tid >> 6, lane = tid & 63;
    const int quad = lane >> 4, rr = lane & 15;
    const int bh = blockIdx.x, q0 = blockIdx.y * 64;
    const int b = bh >> 4, h = bh & 15;
    const int hasbias = *biasflag;

    const float M = __expf(fminf(sml[h], MAX_SCALE_MUL)) * LOG2E;
    const f32x4 negM = (f32x4){-M, -M, -M, -M};

    const unsigned short* Kb = Kh + (size_t)bh * PL * PD;   // (L,D)
    const unsigned short* Vb = Vt + (size_t)bh * PL * PD;   // (D,L)

    // Q B-fragments direct from global: B[n=q=rr][k=d=quad*8+j]
    const size_t qrow = (size_t)bh * PL + q0 + wave * 16 + rr;
    const s16x8 qB0 = *(const s16x8*)(Qh + qrow * PD + quad * 8);
    const s16x8 qB1 = *(const s16x8*)(Qh + qrow * PD + 32 + quad * 8);

    f32x4 accO[4];
#pragma unroll
    for (int jd = 0; jd < 4; jd++) accO[jd] = (f32x4){0.f, 0.f, 0.f, 0.f};
    float lsum = 0.f;

    const int qglob = q0 + wave * 16 + rr;

#pragma unroll 1
    for (int kb = 0; kb < 16; kb++) {
        // ---- K fragments direct from global: A[m=key][k=d] ----
        s16x8 kA[4][2];
#pragma unroll
        for (int s = 0; s < 4; s++) {
            const unsigned short* kp = Kb + (size_t)(kb * 64 + s * 16 + rr) * PD;
            kA[s][0] = *(const s16x8*)(kp + quad * 8);
            kA[s][1] = *(const s16x8*)(kp + 32 + quad * 8);
        }
        f32x4 sc4[4];
#pragma unroll
        for (int s = 0; s < 4; s++) {
            f32x4 z = MFMA16(kA[s][0], qB0, negM);
            z = MFMA16(kA[s][1], qB1, z);
            sc4[s] = z;
        }

        // optional bias (uniform branch; skipped when attn_bias == 0)
        if (hasbias) {
            const float* brow = bias + (size_t)qglob * PL + kb * 64;
#pragma unroll
            for (int s = 0; s < 4; s++) {
                float4 bv = *(const float4*)(brow + s * 16 + quad * 4);
                sc4[s][0] = fmaf(bv.x, LOG2E, sc4[s][0]);
                sc4[s][1] = fmaf(bv.y, LOG2E, sc4[s][1]);
                sc4[s][2] = fmaf(bv.z, LOG2E, sc4[s][2]);
                sc4[s][3] = fmaf(bv.w, LOG2E, sc4[s][3]);
            }
        }

        // ---- softmax: p = exp2(s - M) ----
#pragma unroll
        for (int s = 0; s < 4; s++) {
            sc4[s][0] = EXP2(sc4[s][0]);
            sc4[s][1] = EXP2(sc4[s][1]);
            sc4[s][2] = EXP2(sc4[s][2]);
            sc4[s][3] = EXP2(sc4[s][3]);
            lsum += sc4[s][0] + sc4[s][1] + sc4[s][2] + sc4[s][3];
        }

        // ---- V^T fragments direct from global: A[m=d][k=key] ----
        s16x8 vA[4][2];
#pragma unroll
        for (int s = 0; s < 4; s++) {
            const unsigned short* vp = Vb + (size_t)(s * 16 + rr) * PL + kb * 64;
            vA[s][0] = *(const s16x8*)(vp + quad * 8);
            vA[s][1] = *(const s16x8*)(vp + 32 + quad * 8);
        }

        // ---- P^T repack via wave-private LDS (no barrier needed) ----
#pragma unroll
        for (int s = 0; s < 4; s++) {
            *(uint2*)&Ps[wave][rr * 36 + s * 8 + quad * 2] =
                make_uint2(pk2bf(sc4[s][0], sc4[s][1]),
                           pk2bf(sc4[s][2], sc4[s][3]));
        }
        s16x8 pB0 = *(const s16x8*)&Ps[wave][rr * 36 + quad * 4];
        s16x8 pB1 = *(const s16x8*)&Ps[wave][rr * 36 + 16 + quad * 4];

        // ---- O^T += V^T . P^T ----
#pragma unroll
        for (int jd = 0; jd < 4; jd++) {
            accO[jd] = MFMA16(vA[jd][0], pB0, accO[jd]);
            accO[jd] = MFMA16(vA[jd][1], pB1, accO[jd]);
        }
    }

    // final l reduction across quads; epilogue via per-wave LDS transpose
    lsum += __shfl_xor(lsum, 16);
    lsum += __shfl_xor(lsum, 32);
    float inv = 1.0f / lsum;
#pragma unroll
    for (int jd = 0; jd < 4; jd++) {
        *(uint2*)&Ps[wave][rr * 36 + jd * 8 + quad * 2] =
            make_uint2(pk2bf(accO[jd][0] * inv, accO[jd][1] * inv),
                       pk2bf(accO[jd][2] * inv, accO[jd][3] * inv));
    }
    const int lr = lane >> 2, cch = lane & 3;
    uint4 w0 = *(const uint4*)&Ps[wave][lr * 36 + cch * 8];
    uint4 w1 = *(const uint4*)&Ps[wave][lr * 36 + cch * 8 + 4];
    size_t ob = ((size_t)(b * PL + q0 + wave * 16 + lr) * PC + h * PD);
    *(uint4*)(O + ob + cch * 16)     = w0;
    *(uint4*)(O + ob + cch * 16 + 8) = w1;
}

// ---------------------------------------------------------------------------
// Kernel 4: out-proj GEMM (bf16 MFMA). Out = Oh(8192x1024).Wph(1024x1024)^T + bp
// ---------------------------------------------------------------------------
__global__ __launch_bounds__(256) void gemm_proj_mfma(
    const unsigned short* __restrict__ Ah,
    const unsigned short* __restrict__ Wh,
    const float* __restrict__ bp, float* __restrict__ Out)
{
    __shared__ unsigned short As[128 * 32];
    __shared__ unsigned short Bs[128 * 32];
    const int tid  = threadIdx.x;
    const int wave = tid >> 6, lane = tid & 63;
    const int wm = wave & 1, wn = wave >> 1;
    const int quad = lane >> 4, rr = lane & 15;
    const int m0 = blockIdx.x * 128, n0 = blockIdx.y * 128;

    f32x4 acc[4][4];
#pragma unroll
    for (int i = 0; i < 4; i++)
#pragma unroll
        for (int j = 0; j < 4; j++) acc[i][j] = (f32x4){0.f, 0.f, 0.f, 0.f};

    const int rw = lane >> 2;
    const int cc = lane & 3;
    const int g  = cc ^ ((rw >> 1) & 3);
    const int srow = wave * 32 + rw;
    const unsigned short* gA0 = Ah + (size_t)(m0 + srow) * 1024 + g * 8;
    const unsigned short* gA1 = gA0 + (size_t)16 * 1024;
    const unsigned short* gB0 = Wh + (size_t)(n0 + srow) * 1024 + g * 8;
    const unsigned short* gB1 = gB0 + (size_t)16 * 1024;
    unsigned short* lA0 = &As[(wave * 32) * 32];
    unsigned short* lA1 = &As[(wave * 32 + 16) * 32];
    unsigned short* lB0 = &Bs[(wave * 32) * 32];
    unsigned short* lB1 = &Bs[(wave * 32 + 16) * 32];

    const int swz = (rr >> 1) & 3;
    const int coff = ((quad ^ swz) * 8);

    for (int k0 = 0; k0 < 1024; k0 += 32) {
        gl2lds16(gA0, lA0); gl2lds16(gA1, lA1);
        gl2lds16(gB0, lB0); gl2lds16(gB1, lB1);
        gA0 += 32; gA1 += 32; gB0 += 32; gB1 += 32;
        __syncthreads();

        s16x8 af[4], bf[4];
#pragma unroll
        for (int i = 0; i < 4; i++)
            af[i] = *(const s16x8*)&As[(wm * 64 + i * 16 + rr) * 32 + coff];
#pragma unroll
        for (int j = 0; j < 4; j++)
            bf[j] = *(const s16x8*)&Bs[(wn * 64 + j * 16 + rr) * 32 + coff];
#pragma unroll
        for (int i = 0; i < 4; i++)
#pragma unroll
            for (int j = 0; j < 4; j++)
                acc[i][j] = MFMA16(af[i], bf[j], acc[i][j]);
        __syncthreads();
    }

#pragma unroll
    for (int i = 0; i < 4; i++) {
        const int mb = m0 + wm * 64 + i * 16 + quad * 4;
#pragma unroll
        for (int j = 0; j < 4; j++) {
            const int n = n0 + wn * 64 + j * 16 + rr;
            const float bb = bp[n];
#pragma unroll
            for (int reg = 0; reg < 4; reg++)
                Out[(size_t)(mb + reg) * 1024 + n] = acc[i][j][reg] + bb;
        }
    }
}

// ---------------------------------------------------------------------------
extern "C" void kernel_launch(void* const* d_in, const int* in_sizes, int n_in,
                              void* d_out, int out_size, void* d_ws, size_t ws_size,
                              hipStream_t stream)
{
    const float* x         = (const float*)d_in[0];
    const float* freqs     = (const float*)d_in[1];
    const float* attn_bias = (const float*)d_in[2];
    const float* W_qkv     = (const float*)d_in[3];
    const float* q_bias    = (const float*)d_in[4];
    const float* v_bias    = (const float*)d_in[5];
    const float* sml       = (const float*)d_in[6];
    const float* W_proj    = (const float*)d_in[7];
    const float* b_proj    = (const float*)d_in[8];
    float* out = (float*)d_out;

    unsigned char* w = (unsigned char*)d_ws;
    const size_t MB = 1ull << 20;
    unsigned short* xh  = (unsigned short*)(w + 0);        // 16 MiB
    unsigned short* wqh = (unsigned short*)(w + 16 * MB);  //  6 MiB
    unsigned short* wph = (unsigned short*)(w + 22 * MB);  //  2 MiB
    unsigned short* Qh  = (unsigned short*)(w + 24 * MB);  // 16 MiB (in-place norm+rope)
    unsigned short* Kh  = (unsigned short*)(w + 40 * MB);  // 16 MiB (in-place norm+rope)
    unsigned short* Vh  = (unsigned short*)(w + 56 * MB);  // 16 MiB raw V (B,H,L,D)
    unsigned short* Vt  = (unsigned short*)(w + 72 * MB);  // 16 MiB (B,H,D,L)
    unsigned short* Oh  = (unsigned short*)(w + 88 * MB);  // 16 MiB (B,L,H,D)
    int*            flg = (int*)(w + 104 * MB);            //  4 B bias flag

    // 0. bias flag (ws is poisoned 0xAA -> must zero first)
    hipMemsetAsync(flg, 0, sizeof(int), stream);
    bias_flag_kernel<<<256, 256, 0, stream>>>(attn_bias, flg);
    // 1. fused casts
    cast3_kernel<<<12288, 256, 0, stream>>>(x, W_qkv, W_proj, xh, wqh, wph);
    // 2. lean QKV projection (transposed compute, packed epilogue)
    gemm_qkv_lean<<<dim3(64, 24), 256, 0, stream>>>(xh, wqh, q_bias, v_bias, Qh, Kh, Vh);
    // 3. fused postprocess: Q/K norm+RoPE in place, V transpose
    postproc_kernel<<<34816, 256, 0, stream>>>(Qh, Kh, Vh, Vt, freqs, sml);
    // 4. flash attention (zero-barrier K-loop, direct-global fragments)
    attn_mfma<<<dim3(128, 16), 256, 0, stream>>>(Qh, Kh, Vt, attn_bias, sml, flg, Oh);
    // 5. output projection
    gemm_proj_mfma<<<dim3(64, 8), 256, 0, stream>>>(Oh, wph, b_proj, out);
}

// Round 10
// 292.037 us; speedup vs baseline: 1.5593x; 1.5593x over previous
//
#include <hip/hip_runtime.h>
#include <math.h>

#define PB 8
#define PL 1024
#define PC 1024
#define PH 16
#define PD 64
#define MAX_SCALE_MUL 4.605170185988092f  // log(100)
#define LOG2E 1.4426950408889634f

typedef __attribute__((ext_vector_type(8))) short s16x8;
typedef __attribute__((ext_vector_type(4))) float f32x4;

#define MFMA16(a, b, c) __builtin_amdgcn_mfma_f32_16x16x32_bf16(a, b, c, 0, 0, 0)

#if __has_builtin(__builtin_amdgcn_exp2f)
#define EXP2(x) __builtin_amdgcn_exp2f(x)
#else
#define EXP2(x) exp2f(x)
#endif

// fp32 -> bf16 round-to-nearest-even (scalar fallback path)
__device__ __forceinline__ unsigned short f2bf(float f) {
    unsigned u = __float_as_uint(f);
    unsigned r = (u + 0x7fffu + ((u >> 16) & 1u)) >> 16;
    return (unsigned short)r;
}

// packed pair fp32x2 -> bf16x2 (low = a, high = b)
__device__ __forceinline__ unsigned pk2bf(float a, float b) {
#if __has_builtin(__builtin_amdgcn_cvt_pk_bf16_f32)
    typedef __attribute__((ext_vector_type(2))) __bf16 bf16x2_t;
    bf16x2_t r = __builtin_amdgcn_cvt_pk_bf16_f32(a, b);
    return __builtin_bit_cast(unsigned, r);
#else
    return (unsigned)f2bf(a) | ((unsigned)f2bf(b) << 16);
#endif
}

// async global->LDS, 16 bytes per lane; lptr must be wave-uniform
__device__ __forceinline__ void gl2lds16(const void* g, void* l) {
    __builtin_amdgcn_global_load_lds(
        (const __attribute__((address_space(1))) unsigned int*)g,
        (__attribute__((address_space(3))) unsigned int*)l, 16, 0, 0);
}

// ---------------------------------------------------------------------------
// bias nonzero scan: 256 blocks x 256 threads x 4 float4 = 1M floats
// ---------------------------------------------------------------------------
__global__ __launch_bounds__(256) void bias_flag_kernel(
    const float* __restrict__ bias, int* __restrict__ flag)
{
    int idx = blockIdx.x * 256 + threadIdx.x;
    const float4* b4 = (const float4*)bias;
    bool nz = false;
#pragma unroll
    for (int i = 0; i < 4; i++) {
        float4 v = b4[idx * 4 + i];
        nz |= (v.x != 0.f) | (v.y != 0.f) | (v.z != 0.f) | (v.w != 0.f);
    }
    if (nz) atomicOr(flag, 1);
}

// ---------------------------------------------------------------------------
// cast fp32 -> bf16 for x, W_qkv, W_proj in one launch.
// ---------------------------------------------------------------------------
__global__ __launch_bounds__(256) void cast3_kernel(
    const float* __restrict__ a, const float* __restrict__ b,
    const float* __restrict__ c,
    unsigned short* __restrict__ oa, unsigned short* __restrict__ ob,
    unsigned short* __restrict__ oc)
{
    int blk = blockIdx.x;
    const float* src; unsigned short* dst; int base;
    if (blk < 8192)       { src = a; dst = oa; base = blk; }
    else if (blk < 11264) { src = b; dst = ob; base = blk - 8192; }
    else                  { src = c; dst = oc; base = blk - 11264; }
    int i = base * 256 + threadIdx.x;
    float4 v = ((const float4*)src)[i];
    ((uint2*)dst)[i] = make_uint2(pk2bf(v.x, v.y), pk2bf(v.z, v.w));
}

// ---------------------------------------------------------------------------
// Kernel 1: LEAN QKV GEMM (bf16 MFMA), TRANSPOSED compute: C^T = W . X^T.
// A-operand = W rows (n/d dim), B-operand = X rows (m/l dim), so C/D has
// d in quad*4+reg (contiguous per lane) and l in rr. Epilogue is 16 packed
// 8-byte stores per lane instead of 64 scattered 2-byte stores (R8 lesson).
// ---------------------------------------------------------------------------
__global__ __launch_bounds__(256) void gemm_qkv_lean(
    const unsigned short* __restrict__ Xh,
    const unsigned short* __restrict__ Wh,
    const float* __restrict__ qb, const float* __restrict__ vb,
    unsigned short* __restrict__ Qh, unsigned short* __restrict__ Kh,
    unsigned short* __restrict__ Vh)
{
    __shared__ unsigned short As[128 * 32];
    __shared__ unsigned short Bs[128 * 32];
    const int tid  = threadIdx.x;
    const int wave = tid >> 6, lane = tid & 63;
    const int wm = wave & 1, wn = wave >> 1;
    const int quad = lane >> 4, rr = lane & 15;
    const int m0 = blockIdx.x * 128, n0 = blockIdx.y * 128;

    f32x4 acc[4][4];   // acc[i][j]: i over n(d) sub-tiles, j over m(l) sub-tiles
#pragma unroll
    for (int i = 0; i < 4; i++)
#pragma unroll
        for (int j = 0; j < 4; j++) acc[i][j] = (f32x4){0.f, 0.f, 0.f, 0.f};

    const int rw = lane >> 2;
    const int cc = lane & 3;
    const int g  = cc ^ ((rw >> 1) & 3);
    const int srow = wave * 32 + rw;
    const unsigned short* gA0 = Xh + (size_t)(m0 + srow) * 1024 + g * 8;
    const unsigned short* gA1 = gA0 + (size_t)16 * 1024;
    const unsigned short* gB0 = Wh + (size_t)(n0 + srow) * 1024 + g * 8;
    const unsigned short* gB1 = gB0 + (size_t)16 * 1024;
    unsigned short* lA0 = &As[(wave * 32) * 32];
    unsigned short* lA1 = &As[(wave * 32 + 16) * 32];
    unsigned short* lB0 = &Bs[(wave * 32) * 32];
    unsigned short* lB1 = &Bs[(wave * 32 + 16) * 32];

    const int swz = (rr >> 1) & 3;
    const int coff = ((quad ^ swz) * 8);

    for (int k0 = 0; k0 < 1024; k0 += 32) {
        gl2lds16(gA0, lA0); gl2lds16(gA1, lA1);
        gl2lds16(gB0, lB0); gl2lds16(gB1, lB1);
        gA0 += 32; gA1 += 32; gB0 += 32; gB1 += 32;
        __syncthreads();

        s16x8 wf[4], xf[4];
#pragma unroll
        for (int i = 0; i < 4; i++)
            wf[i] = *(const s16x8*)&Bs[(wn * 64 + i * 16 + rr) * 32 + coff];
#pragma unroll
        for (int j = 0; j < 4; j++)
            xf[j] = *(const s16x8*)&As[(wm * 64 + j * 16 + rr) * 32 + coff];
#pragma unroll
        for (int i = 0; i < 4; i++)
#pragma unroll
            for (int j = 0; j < 4; j++)
                acc[i][j] = MFMA16(wf[i], xf[j], acc[i][j]);
        __syncthreads();
    }

    // epilogue: d = wn*64 + i*16 + quad*4 + reg (contiguous per lane),
    //           l = lb0 + j*16 + rr.  Packed 8B stores.
    const int b     = m0 >> 10;
    const int which = n0 >> 10;                       // 0=Q 1=K 2=V (uniform)
    const int h     = ((n0 & 1023) + wn * 64) >> 6;   // head (uniform per wave)
    const int lb0   = (m0 & 1023) + wm * 64;
    unsigned short* dst = (which == 0) ? Qh : ((which == 1) ? Kh : Vh);
    unsigned short* base = dst + ((size_t)(b * PH + h) * PL) * PD;
    const float* bvec = (which == 0) ? qb : vb;

#pragma unroll
    for (int i = 0; i < 4; i++) {
        const int d0 = i * 16 + quad * 4;             // within-head d, +reg
        float4 b4 = make_float4(0.f, 0.f, 0.f, 0.f);
        if (which != 1) b4 = *(const float4*)(bvec + h * 64 + d0);
#pragma unroll
        for (int j = 0; j < 4; j++) {
            const int l = lb0 + j * 16 + rr;
            uint2 pk = make_uint2(
                pk2bf(acc[i][j][0] + b4.x, acc[i][j][1] + b4.y),
                pk2bf(acc[i][j][2] + b4.z, acc[i][j][3] + b4.w));
            *(uint2*)(base + (size_t)l * PD + d0) = pk;
        }
    }
}

// ---------------------------------------------------------------------------
// Kernel 2: fused postprocess (3 roles by block range).
//  [0,16384):      Q norm + *exp(min(sml,MAX))*log2e + RoPE, in place (bf16)
//  [16384,32768):  K norm + RoPE, in place (bf16)
//  [32768,34816):  V transpose (B,H,L,D) -> (B,H,D,L)
// ---------------------------------------------------------------------------
__global__ __launch_bounds__(256) void postproc_kernel(
    unsigned short* __restrict__ Qh, unsigned short* __restrict__ Kh,
    const unsigned short* __restrict__ Vh, unsigned short* __restrict__ Vt,
    const float* __restrict__ freqs, const float* __restrict__ sml)
{
    const int blk = blockIdx.x;
    const int tid = threadIdx.x;

    if (blk < 32768) {
        const bool isQ = blk < 16384;
        const int rb = isQ ? blk : blk - 16384;
        const int row = rb * 8 + (tid >> 5);       // 8 rows per block
        const int li  = tid & 31;                  // pair index within row
        const int h = (row >> 10) & (PH - 1);
        const int l = row & (PL - 1);

        unsigned short* buf = isQ ? Qh : Kh;
        unsigned* p = (unsigned*)(buf + (size_t)row * PD) + li;
        unsigned v = *p;
        float v0 = __uint_as_float(v << 16);
        float v1 = __uint_as_float(v & 0xffff0000u);

        float ss = fmaf(v0, v0, v1 * v1);
#pragma unroll
        for (int off = 1; off <= 16; off <<= 1) ss += __shfl_xor(ss, off);

        float smul = isQ ? (__expf(fminf(sml[h], MAX_SCALE_MUL)) * LOG2E) : 1.0f;
        float scale = smul / fmaxf(sqrtf(ss), 1e-12f);
        v0 *= scale; v1 *= scale;

        float2 cs = ((const float2*)freqs)[l * 32 + li];
        float re = v0 * cs.x - v1 * cs.y;
        float im = fmaf(v0, cs.y, v1 * cs.x);
        *p = pk2bf(re, im);
        return;
    }

    // V transpose
    const int vblk = blk - 32768;
    const int bh = vblk >> 4;
    const int l0 = (vblk & 15) * 64;
#pragma unroll
    for (int s = 0; s < 2; s++) {
        int slot = s * 256 + tid;
        int d  = slot & 63;
        int lb = l0 + (slot >> 6) * 8;
        unsigned o[4];
#pragma unroll
        for (int i = 0; i < 4; i++) {
            unsigned short a0 = Vh[((size_t)bh * PL + lb + 2 * i) * PD + d];
            unsigned short a1 = Vh[((size_t)bh * PL + lb + 2 * i + 1) * PD + d];
            o[i] = (unsigned)a0 | ((unsigned)a1 << 16);
        }
        *(uint4*)&Vt[((size_t)bh * PD + d) * PL + lb] = make_uint4(o[0], o[1], o[2], o[3]);
    }
}

// ---------------------------------------------------------------------------
// Kernel 3: flash attention, Q-tile 128, SINGLE-buffered LDS K/V staging
// (R8 structure restored verbatim: R9 proved direct-global fragments are
// latency-bound, 3.4x worse; LDS staging + wave overlap is the sweet spot).
// Static-bound softmax with -M folded into MFMA C-init; bias-skip flag.
// grid = (bh, qtile): same-bh blocks are 128 apart (== 0 mod 8) -> same XCD.
// ---------------------------------------------------------------------------
__global__ __launch_bounds__(256) void attn_mfma(
    const unsigned short* __restrict__ Qh, const unsigned short* __restrict__ Kh,
    const unsigned short* __restrict__ Vt, const float* __restrict__ bias,
    const float* __restrict__ sml, const int* __restrict__ biasflag,
    unsigned short* __restrict__ O)
{
    __shared__ unsigned short Ks[64 * 64];
    __shared__ unsigned short Vs[64 * 64];
    __shared__ unsigned int   Ps[4][16 * 36];   // per-wave P^T pairs, stride 36

    const int tid  = threadIdx.x;
    const int wave = tid >> 6, lane = tid & 63;
    const int quad = lane >> 4, rr = lane & 15;
    const int bh = blockIdx.x, q0 = blockIdx.y * 128;
    const int b = bh >> 4, h = bh & 15;
    const int hasbias = *biasflag;

    const float M = __expf(fminf(sml[h], MAX_SCALE_MUL)) * LOG2E;
    const f32x4 negM = (f32x4){-M, -M, -M, -M};

    const int sr = wave * 16 + (lane >> 3);
    const int sc = lane & 7;
    const int sg = sc ^ (sr & 7);               // swizzled global chunk
    const int swz8 = rr & 7;

    const size_t kvbase = (size_t)bh * PL * PD; // ELEMENT offset into K/V

    // Q B-fragments for both q-groups, direct from global (row index * PD)
    s16x8 qB[2][2];
#pragma unroll
    for (int g = 0; g < 2; g++) {
        const size_t qrow = (size_t)bh * PL + q0 + g * 64 + wave * 16 + rr;
        qB[g][0] = *(const s16x8*)(Qh + qrow * PD + quad * 8);
        qB[g][1] = *(const s16x8*)(Qh + qrow * PD + 32 + quad * 8);
    }

    f32x4 accO[2][4];
#pragma unroll
    for (int g = 0; g < 2; g++)
#pragma unroll
        for (int jd = 0; jd < 4; jd++) accO[g][jd] = (f32x4){0.f, 0.f, 0.f, 0.f};
    float lsum[2] = {0.f, 0.f};

    for (int kb = 0; kb < 16; kb++) {
        gl2lds16(Kh + kvbase + (size_t)(kb * 64 + sr) * PD + sg * 8, &Ks[(wave * 16) * 64]);
        gl2lds16(Kh + kvbase + (size_t)(kb * 64 + sr + 8) * PD + sg * 8, &Ks[(wave * 16 + 8) * 64]);
        gl2lds16(Vt + kvbase + (size_t)sr * PL + kb * 64 + sg * 8, &Vs[(wave * 16) * 64]);
        gl2lds16(Vt + kvbase + (size_t)(sr + 8) * PL + kb * 64 + sg * 8, &Vs[(wave * 16 + 8) * 64]);
        __syncthreads();

        // ---- phase 1: S^T - M for both q-groups (kA live) ----
        s16x8 kA[4][2];
#pragma unroll
        for (int s = 0; s < 4; s++) {
            kA[s][0] = *(const s16x8*)&Ks[(s * 16 + rr) * 64 + ((0 + quad) ^ swz8) * 8];
            kA[s][1] = *(const s16x8*)&Ks[(s * 16 + rr) * 64 + ((4 + quad) ^ swz8) * 8];
        }
        f32x4 sc4[2][4];
#pragma unroll
        for (int g = 0; g < 2; g++)
#pragma unroll
            for (int s = 0; s < 4; s++) {
                f32x4 z = MFMA16(kA[s][0], qB[g][0], negM);
                z = MFMA16(kA[s][1], qB[g][1], z);
                sc4[g][s] = z;
            }

        // optional bias (uniform branch; skipped when attn_bias == 0)
        if (hasbias) {
#pragma unroll
            for (int g = 0; g < 2; g++) {
                const float* brow = bias + (size_t)(q0 + g * 64 + wave * 16 + rr) * PL + kb * 64;
#pragma unroll
                for (int s = 0; s < 4; s++) {
                    float4 bv = *(const float4*)(brow + s * 16 + quad * 4);
                    sc4[g][s][0] = fmaf(bv.x, LOG2E, sc4[g][s][0]);
                    sc4[g][s][1] = fmaf(bv.y, LOG2E, sc4[g][s][1]);
                    sc4[g][s][2] = fmaf(bv.z, LOG2E, sc4[g][s][2]);
                    sc4[g][s][3] = fmaf(bv.w, LOG2E, sc4[g][s][3]);
                }
            }
        }

        // ---- softmax: p = exp2(s - M) ----
#pragma unroll
        for (int g = 0; g < 2; g++)
#pragma unroll
            for (int s = 0; s < 4; s++) {
                sc4[g][s][0] = EXP2(sc4[g][s][0]);
                sc4[g][s][1] = EXP2(sc4[g][s][1]);
                sc4[g][s][2] = EXP2(sc4[g][s][2]);
                sc4[g][s][3] = EXP2(sc4[g][s][3]);
                lsum[g] += sc4[g][s][0] + sc4[g][s][1] + sc4[g][s][2] + sc4[g][s][3];
            }

        // ---- phase 2: PV for both q-groups (vA live; Ps reused per group) ----
        s16x8 vA[4][2];
#pragma unroll
        for (int s = 0; s < 4; s++) {
            vA[s][0] = *(const s16x8*)&Vs[(s * 16 + rr) * 64 + ((0 + quad) ^ swz8) * 8];
            vA[s][1] = *(const s16x8*)&Vs[(s * 16 + rr) * 64 + ((4 + quad) ^ swz8) * 8];
        }
#pragma unroll
        for (int g = 0; g < 2; g++) {
#pragma unroll
            for (int s = 0; s < 4; s++) {
                *(uint2*)&Ps[wave][rr * 36 + s * 8 + quad * 2] =
                    make_uint2(pk2bf(sc4[g][s][0], sc4[g][s][1]),
                               pk2bf(sc4[g][s][2], sc4[g][s][3]));
            }
            // same-wave LDS ops are in-order: no barrier needed
            s16x8 pB0 = *(const s16x8*)&Ps[wave][rr * 36 + quad * 4];
            s16x8 pB1 = *(const s16x8*)&Ps[wave][rr * 36 + 16 + quad * 4];
#pragma unroll
            for (int jd = 0; jd < 4; jd++) {
                accO[g][jd] = MFMA16(vA[jd][0], pB0, accO[g][jd]);
                accO[g][jd] = MFMA16(vA[jd][1], pB1, accO[g][jd]);
            }
        }
        __syncthreads();
    }

    // final l reduction across quads; epilogue via per-wave LDS transpose
    const int lr = lane >> 2, cch = lane & 3;
#pragma unroll
    for (int g = 0; g < 2; g++) {
        float ls = lsum[g];
        ls += __shfl_xor(ls, 16);
        ls += __shfl_xor(ls, 32);
        float inv = 1.0f / ls;
#pragma unroll
        for (int jd = 0; jd < 4; jd++) {
            *(uint2*)&Ps[wave][rr * 36 + jd * 8 + quad * 2] =
                make_uint2(pk2bf(accO[g][jd][0] * inv, accO[g][jd][1] * inv),
                           pk2bf(accO[g][jd][2] * inv, accO[g][jd][3] * inv));
        }
        uint4 w0 = *(const uint4*)&Ps[wave][lr * 36 + cch * 8];
        uint4 w1 = *(const uint4*)&Ps[wave][lr * 36 + cch * 8 + 4];
        size_t ob = ((size_t)(b * PL + q0 + g * 64 + wave * 16 + lr) * PC + h * PD);
        *(uint4*)(O + ob + cch * 16)     = w0;
        *(uint4*)(O + ob + cch * 16 + 8) = w1;
    }
}

// ---------------------------------------------------------------------------
// Kernel 4: out-proj GEMM (bf16 MFMA). Out = Oh(8192x1024).Wph(1024x1024)^T + bp
// ---------------------------------------------------------------------------
__global__ __launch_bounds__(256) void gemm_proj_mfma(
    const unsigned short* __restrict__ Ah,
    const unsigned short* __restrict__ Wh,
    const float* __restrict__ bp, float* __restrict__ Out)
{
    __shared__ unsigned short As[128 * 32];
    __shared__ unsigned short Bs[128 * 32];
    const int tid  = threadIdx.x;
    const int wave = tid >> 6, lane = tid & 63;
    const int wm = wave & 1, wn = wave >> 1;
    const int quad = lane >> 4, rr = lane & 15;
    const int m0 = blockIdx.x * 128, n0 = blockIdx.y * 128;

    f32x4 acc[4][4];
#pragma unroll
    for (int i = 0; i < 4; i++)
#pragma unroll
        for (int j = 0; j < 4; j++) acc[i][j] = (f32x4){0.f, 0.f, 0.f, 0.f};

    const int rw = lane >> 2;
    const int cc = lane & 3;
    const int g  = cc ^ ((rw >> 1) & 3);
    const int srow = wave * 32 + rw;
    const unsigned short* gA0 = Ah + (size_t)(m0 + srow) * 1024 + g * 8;
    const unsigned short* gA1 = gA0 + (size_t)16 * 1024;
    const unsigned short* gB0 = Wh + (size_t)(n0 + srow) * 1024 + g * 8;
    const unsigned short* gB1 = gB0 + (size_t)16 * 1024;
    unsigned short* lA0 = &As[(wave * 32) * 32];
    unsigned short* lA1 = &As[(wave * 32 + 16) * 32];
    unsigned short* lB0 = &Bs[(wave * 32) * 32];
    unsigned short* lB1 = &Bs[(wave * 32 + 16) * 32];

    const int swz = (rr >> 1) & 3;
    const int coff = ((quad ^ swz) * 8);

    for (int k0 = 0; k0 < 1024; k0 += 32) {
        gl2lds16(gA0, lA0); gl2lds16(gA1, lA1);
        gl2lds16(gB0, lB0); gl2lds16(gB1, lB1);
        gA0 += 32; gA1 += 32; gB0 += 32; gB1 += 32;
        __syncthreads();

        s16x8 af[4], bf[4];
#pragma unroll
        for (int i = 0; i < 4; i++)
            af[i] = *(const s16x8*)&As[(wm * 64 + i * 16 + rr) * 32 + coff];
#pragma unroll
        for (int j = 0; j < 4; j++)
            bf[j] = *(const s16x8*)&Bs[(wn * 64 + j * 16 + rr) * 32 + coff];
#pragma unroll
        for (int i = 0; i < 4; i++)
#pragma unroll
            for (int j = 0; j < 4; j++)
                acc[i][j] = MFMA16(af[i], bf[j], acc[i][j]);
        __syncthreads();
    }

#pragma unroll
    for (int i = 0; i < 4; i++) {
        const int mb = m0 + wm * 64 + i * 16 + quad * 4;
#pragma unroll
        for (int j = 0; j < 4; j++) {
            const int n = n0 + wn * 64 + j * 16 + rr;
            const float bb = bp[n];
#pragma unroll
            for (int reg = 0; reg < 4; reg++)
                Out[(size_t)(mb + reg) * 1024 + n] = acc[i][j][reg] + bb;
        }
    }
}

// ---------------------------------------------------------------------------
extern "C" void kernel_launch(void* const* d_in, const int* in_sizes, int n_in,
                              void* d_out, int out_size, void* d_ws, size_t ws_size,
                              hipStream_t stream)
{
    const float* x         = (const float*)d_in[0];
    const float* freqs     = (const float*)d_in[1];
    const float* attn_bias = (const float*)d_in[2];
    const float* W_qkv     = (const float*)d_in[3];
    const float* q_bias    = (const float*)d_in[4];
    const float* v_bias    = (const float*)d_in[5];
    const float* sml       = (const float*)d_in[6];
    const float* W_proj    = (const float*)d_in[7];
    const float* b_proj    = (const float*)d_in[8];
    float* out = (float*)d_out;

    unsigned char* w = (unsigned char*)d_ws;
    const size_t MB = 1ull << 20;
    unsigned short* xh  = (unsigned short*)(w + 0);        // 16 MiB
    unsigned short* wqh = (unsigned short*)(w + 16 * MB);  //  6 MiB
    unsigned short* wph = (unsigned short*)(w + 22 * MB);  //  2 MiB
    unsigned short* Qh  = (unsigned short*)(w + 24 * MB);  // 16 MiB (in-place norm+rope)
    unsigned short* Kh  = (unsigned short*)(w + 40 * MB);  // 16 MiB (in-place norm+rope)
    unsigned short* Vh  = (unsigned short*)(w + 56 * MB);  // 16 MiB raw V (B,H,L,D)
    unsigned short* Vt  = (unsigned short*)(w + 72 * MB);  // 16 MiB (B,H,D,L)
    unsigned short* Oh  = (unsigned short*)(w + 88 * MB);  // 16 MiB (B,L,H,D)
    int*            flg = (int*)(w + 104 * MB);            //  4 B bias flag

    // 0. bias flag (ws is poisoned 0xAA -> must zero first)
    hipMemsetAsync(flg, 0, sizeof(int), stream);
    bias_flag_kernel<<<256, 256, 0, stream>>>(attn_bias, flg);
    // 1. fused casts
    cast3_kernel<<<12288, 256, 0, stream>>>(x, W_qkv, W_proj, xh, wqh, wph);
    // 2. lean QKV projection (transposed compute, packed epilogue)
    gemm_qkv_lean<<<dim3(64, 24), 256, 0, stream>>>(xh, wqh, q_bias, v_bias, Qh, Kh, Vh);
    // 3. fused postprocess: Q/K norm+RoPE in place, V transpose
    postproc_kernel<<<34816, 256, 0, stream>>>(Qh, Kh, Vh, Vt, freqs, sml);
    // 4. flash attention (R8 structure: LDS-staged, Q-tile 128, XCD-local)
    attn_mfma<<<dim3(128, 8), 256, 0, stream>>>(Qh, Kh, Vt, attn_bias, sml, flg, Oh);
    // 5. output projection
    gemm_proj_mfma<<<dim3(64, 8), 256, 0, stream>>>(Oh, wph, b_proj, out);
}

// Round 11
// 282.578 us; speedup vs baseline: 1.6115x; 1.0335x over previous
//
#include <hip/hip_runtime.h>
#include <math.h>

#define PB 8
#define PL 1024
#define PC 1024
#define PH 16
#define PD 64
#define MAX_SCALE_MUL 4.605170185988092f  // log(100)
#define LOG2E 1.4426950408889634f

typedef __attribute__((ext_vector_type(8))) short s16x8;
typedef __attribute__((ext_vector_type(4))) float f32x4;

#define MFMA16(a, b, c) __builtin_amdgcn_mfma_f32_16x16x32_bf16(a, b, c, 0, 0, 0)

#if __has_builtin(__builtin_amdgcn_exp2f)
#define EXP2(x) __builtin_amdgcn_exp2f(x)
#else
#define EXP2(x) exp2f(x)
#endif

// fp32 -> bf16 round-to-nearest-even (scalar fallback path)
__device__ __forceinline__ unsigned short f2bf(float f) {
    unsigned u = __float_as_uint(f);
    unsigned r = (u + 0x7fffu + ((u >> 16) & 1u)) >> 16;
    return (unsigned short)r;
}

// packed pair fp32x2 -> bf16x2 (low = a, high = b)
__device__ __forceinline__ unsigned pk2bf(float a, float b) {
#if __has_builtin(__builtin_amdgcn_cvt_pk_bf16_f32)
    typedef __attribute__((ext_vector_type(2))) __bf16 bf16x2_t;
    bf16x2_t r = __builtin_amdgcn_cvt_pk_bf16_f32(a, b);
    return __builtin_bit_cast(unsigned, r);
#else
    return (unsigned)f2bf(a) | ((unsigned)f2bf(b) << 16);
#endif
}

// async global->LDS, 16 bytes per lane; lptr must be wave-uniform
__device__ __forceinline__ void gl2lds16(const void* g, void* l) {
    __builtin_amdgcn_global_load_lds(
        (const __attribute__((address_space(1))) unsigned int*)g,
        (__attribute__((address_space(3))) unsigned int*)l, 16, 0, 0);
}

// ---------------------------------------------------------------------------
// cast fp32 -> bf16 for x, W_qkv, W_proj + attn_bias nonzero scan, one launch.
// blocks [0,8192) -> x, [8192,11264) -> W_qkv, [11264,12288) -> W_proj,
// [12288,12544) -> bias scan (256 blocks x 256 thr x 4 float4 = 1M floats).
// ---------------------------------------------------------------------------
__global__ __launch_bounds__(256) void cast3f_kernel(
    const float* __restrict__ a, const float* __restrict__ b,
    const float* __restrict__ c, const float* __restrict__ bias,
    unsigned short* __restrict__ oa, unsigned short* __restrict__ ob,
    unsigned short* __restrict__ oc, int* __restrict__ flag)
{
    int blk = blockIdx.x;
    if (blk >= 12288) {
        int idx = (blk - 12288) * 256 + threadIdx.x;
        const float4* b4 = (const float4*)bias;
        bool nz = false;
#pragma unroll
        for (int i = 0; i < 4; i++) {
            float4 v = b4[idx * 4 + i];
            nz |= (v.x != 0.f) | (v.y != 0.f) | (v.z != 0.f) | (v.w != 0.f);
        }
        if (nz) atomicOr(flag, 1);
        return;
    }
    const float* src; unsigned short* dst; int base;
    if (blk < 8192)       { src = a; dst = oa; base = blk; }
    else if (blk < 11264) { src = b; dst = ob; base = blk - 8192; }
    else                  { src = c; dst = oc; base = blk - 11264; }
    int i = base * 256 + threadIdx.x;
    float4 v = ((const float4*)src)[i];
    ((uint2*)dst)[i] = make_uint2(pk2bf(v.x, v.y), pk2bf(v.z, v.w));
}

// ---------------------------------------------------------------------------
// Kernel 1: QKV GEMM (bf16 MFMA), transposed compute C^T = W . X^T, BK=64.
// 16 K-iters of (8 staging loads + 32 MFMA/wave) — half the barriers of
// BK=32 (R10: qkv stuck at 71us/29% MfmaUtil = barrier-drain plateau).
// Frags loaded per-kk half to keep VGPR ~110.
// ---------------------------------------------------------------------------
__global__ __launch_bounds__(256) void gemm_qkv_lean(
    const unsigned short* __restrict__ Xh,
    const unsigned short* __restrict__ Wh,
    const float* __restrict__ qb, const float* __restrict__ vb,
    unsigned short* __restrict__ Qh, unsigned short* __restrict__ Kh,
    unsigned short* __restrict__ Vh)
{
    __shared__ unsigned short As[128 * 64];
    __shared__ unsigned short Bs[128 * 64];
    const int tid  = threadIdx.x;
    const int wave = tid >> 6, lane = tid & 63;
    const int wm = wave & 1, wn = wave >> 1;
    const int quad = lane >> 4, rr = lane & 15;
    const int m0 = blockIdx.x * 128, n0 = blockIdx.y * 128;

    f32x4 acc[4][4];   // acc[i][j]: i over n(d) sub-tiles, j over m(l) sub-tiles
#pragma unroll
    for (int i = 0; i < 4; i++)
#pragma unroll
        for (int j = 0; j < 4; j++) acc[i][j] = (f32x4){0.f, 0.f, 0.f, 0.f};

    // staging geometry (BK=64): instr covers 8 rows x 8 chunks of 16B
    const int r8 = lane >> 3;            // row within instr
    const int c8 = lane & 7;             // LDS chunk
    const int g  = c8 ^ r8;              // swizzled global chunk
    const unsigned short* gA = Xh + (size_t)(m0 + wave * 32 + r8) * 1024 + g * 8;
    const unsigned short* gB = Wh + (size_t)(n0 + wave * 32 + r8) * 1024 + g * 8;
    unsigned short* lA = &As[(wave * 32) * 64];
    unsigned short* lB = &Bs[(wave * 32) * 64];

    const int swz8 = rr & 7;

    for (int k0 = 0; k0 < 16; k0++) {
#pragma unroll
        for (int t = 0; t < 4; t++) {
            gl2lds16(gA + (size_t)t * 8192, &lA[(t * 8) * 64]);
            gl2lds16(gB + (size_t)t * 8192, &lB[(t * 8) * 64]);
        }
        gA += 64; gB += 64;
        __syncthreads();

#pragma unroll
        for (int kk = 0; kk < 2; kk++) {
            const int coff = ((kk * 4 + quad) ^ swz8) * 8;
            s16x8 wf[4], xf[4];
#pragma unroll
            for (int i = 0; i < 4; i++)
                wf[i] = *(const s16x8*)&Bs[(wn * 64 + i * 16 + rr) * 64 + coff];
#pragma unroll
            for (int j = 0; j < 4; j++)
                xf[j] = *(const s16x8*)&As[(wm * 64 + j * 16 + rr) * 64 + coff];
#pragma unroll
            for (int i = 0; i < 4; i++)
#pragma unroll
                for (int j = 0; j < 4; j++)
                    acc[i][j] = MFMA16(wf[i], xf[j], acc[i][j]);
        }
        __syncthreads();
    }

    // epilogue: d = wn*64 + i*16 + quad*4 + reg (contiguous), l = lb0+j*16+rr
    const int b     = m0 >> 10;
    const int which = n0 >> 10;                       // 0=Q 1=K 2=V (uniform)
    const int h     = ((n0 & 1023) + wn * 64) >> 6;   // head (uniform per wave)
    const int lb0   = (m0 & 1023) + wm * 64;
    unsigned short* dst = (which == 0) ? Qh : ((which == 1) ? Kh : Vh);
    unsigned short* base = dst + ((size_t)(b * PH + h) * PL) * PD;
    const float* bvec = (which == 0) ? qb : vb;

#pragma unroll
    for (int i = 0; i < 4; i++) {
        const int d0 = i * 16 + quad * 4;
        float4 b4 = make_float4(0.f, 0.f, 0.f, 0.f);
        if (which != 1) b4 = *(const float4*)(bvec + h * 64 + d0);
#pragma unroll
        for (int j = 0; j < 4; j++) {
            const int l = lb0 + j * 16 + rr;
            uint2 pk = make_uint2(
                pk2bf(acc[i][j][0] + b4.x, acc[i][j][1] + b4.y),
                pk2bf(acc[i][j][2] + b4.z, acc[i][j][3] + b4.w));
            *(uint2*)(base + (size_t)l * PD + d0) = pk;
        }
    }
}

// ---------------------------------------------------------------------------
// Kernel 2: postprocess, K + V only (Q norm+RoPE now fused into attn).
//  [0,16384):      K norm + RoPE, in place (bf16)
//  [16384,18432):  V transpose (B,H,L,D) -> (B,H,D,L)
// ---------------------------------------------------------------------------
__global__ __launch_bounds__(256) void postproc_kernel(
    unsigned short* __restrict__ Kh,
    const unsigned short* __restrict__ Vh, unsigned short* __restrict__ Vt,
    const float* __restrict__ freqs)
{
    const int blk = blockIdx.x;
    const int tid = threadIdx.x;

    if (blk < 16384) {
        const int row = blk * 8 + (tid >> 5);      // 8 rows per block
        const int li  = tid & 31;                  // pair index within row
        const int l = row & (PL - 1);

        unsigned* p = (unsigned*)(Kh + (size_t)row * PD) + li;
        unsigned v = *p;
        float v0 = __uint_as_float(v << 16);
        float v1 = __uint_as_float(v & 0xffff0000u);

        float ss = fmaf(v0, v0, v1 * v1);
#pragma unroll
        for (int off = 1; off <= 16; off <<= 1) ss += __shfl_xor(ss, off);

        float scale = 1.0f / fmaxf(sqrtf(ss), 1e-12f);
        v0 *= scale; v1 *= scale;

        float2 cs = ((const float2*)freqs)[l * 32 + li];
        float re = v0 * cs.x - v1 * cs.y;
        float im = fmaf(v0, cs.y, v1 * cs.x);
        *p = pk2bf(re, im);
        return;
    }

    // V transpose
    const int vblk = blk - 16384;
    const int bh = vblk >> 4;
    const int l0 = (vblk & 15) * 64;
#pragma unroll
    for (int s = 0; s < 2; s++) {
        int slot = s * 256 + tid;
        int d  = slot & 63;
        int lb = l0 + (slot >> 6) * 8;
        unsigned o[4];
#pragma unroll
        for (int i = 0; i < 4; i++) {
            unsigned short a0 = Vh[((size_t)bh * PL + lb + 2 * i) * PD + d];
            unsigned short a1 = Vh[((size_t)bh * PL + lb + 2 * i + 1) * PD + d];
            o[i] = (unsigned)a0 | ((unsigned)a1 << 16);
        }
        *(uint4*)&Vt[((size_t)bh * PD + d) * PL + lb] = make_uint4(o[0], o[1], o[2], o[3]);
    }
}

// ---------------------------------------------------------------------------
// Kernel 3: flash attention, R8/R10 structure + in-register Q norm+RoPE.
// Q is read RAW (qkv output, bias applied) and normalized/roped/scaled in
// registers once per block: RoPE pairs are d-contiguous inside the lane's
// fragment, norm = in-lane sum + 2 shfl_xor across quads.
// Static-bound softmax (-M in MFMA C-init); bias-skip flag; XCD-local grid.
// ---------------------------------------------------------------------------
__global__ __launch_bounds__(256) void attn_mfma(
    const unsigned short* __restrict__ Qh, const unsigned short* __restrict__ Kh,
    const unsigned short* __restrict__ Vt, const float* __restrict__ bias,
    const float* __restrict__ sml, const int* __restrict__ biasflag,
    const float* __restrict__ freqs, unsigned short* __restrict__ O)
{
    __shared__ unsigned short Ks[64 * 64];
    __shared__ unsigned short Vs[64 * 64];
    __shared__ unsigned int   Ps[4][16 * 36];   // per-wave P^T pairs, stride 36

    const int tid  = threadIdx.x;
    const int wave = tid >> 6, lane = tid & 63;
    const int quad = lane >> 4, rr = lane & 15;
    const int bh = blockIdx.x, q0 = blockIdx.y * 128;
    const int b = bh >> 4, h = bh & 15;
    const int hasbias = *biasflag;

    const float M = __expf(fminf(sml[h], MAX_SCALE_MUL)) * LOG2E;
    const f32x4 negM = (f32x4){-M, -M, -M, -M};

    const int sr = wave * 16 + (lane >> 3);
    const int sc = lane & 7;
    const int sg = sc ^ (sr & 7);               // swizzled global chunk
    const int swz8 = rr & 7;

    const size_t kvbase = (size_t)bh * PL * PD; // ELEMENT offset into K/V
    const float2* fr2 = (const float2*)freqs;

    // Q fragments: load raw bf16, norm + scale(M) + RoPE in registers.
    s16x8 qB[2][2];
#pragma unroll
    for (int g = 0; g < 2; g++) {
        const int ql = q0 + g * 64 + wave * 16 + rr;
        const size_t qoff = ((size_t)bh * PL + ql) * PD;
        uint4 r0 = *(const uint4*)(Qh + qoff + quad * 8);
        uint4 r1 = *(const uint4*)(Qh + qoff + 32 + quad * 8);
        unsigned uu[8] = {r0.x, r0.y, r0.z, r0.w, r1.x, r1.y, r1.z, r1.w};
        float lo[8], hi[8];
        float ss = 0.f;
#pragma unroll
        for (int m = 0; m < 8; m++) {
            lo[m] = __uint_as_float(uu[m] << 16);
            hi[m] = __uint_as_float(uu[m] & 0xffff0000u);
            ss = fmaf(lo[m], lo[m], fmaf(hi[m], hi[m], ss));
        }
        ss += __shfl_xor(ss, 16);
        ss += __shfl_xor(ss, 32);
        const float scale = M / fmaxf(sqrtf(ss), 1e-12f);
        unsigned outw[8];
#pragma unroll
        for (int m = 0; m < 8; m++) {
            const int idx = (m >> 2) * 16 + quad * 4 + (m & 3);  // freq index
            float2 cs = fr2[(size_t)ql * 32 + idx];
            float av = lo[m] * scale, bv = hi[m] * scale;
            float re = av * cs.x - bv * cs.y;
            float im = fmaf(av, cs.y, bv * cs.x);
            outw[m] = pk2bf(re, im);
        }
        uint4 w0 = make_uint4(outw[0], outw[1], outw[2], outw[3]);
        uint4 w1 = make_uint4(outw[4], outw[5], outw[6], outw[7]);
        qB[g][0] = __builtin_bit_cast(s16x8, w0);
        qB[g][1] = __builtin_bit_cast(s16x8, w1);
    }

    f32x4 accO[2][4];
#pragma unroll
    for (int g = 0; g < 2; g++)
#pragma unroll
        for (int jd = 0; jd < 4; jd++) accO[g][jd] = (f32x4){0.f, 0.f, 0.f, 0.f};
    float lsum[2] = {0.f, 0.f};

    for (int kb = 0; kb < 16; kb++) {
        gl2lds16(Kh + kvbase + (size_t)(kb * 64 + sr) * PD + sg * 8, &Ks[(wave * 16) * 64]);
        gl2lds16(Kh + kvbase + (size_t)(kb * 64 + sr + 8) * PD + sg * 8, &Ks[(wave * 16 + 8) * 64]);
        gl2lds16(Vt + kvbase + (size_t)sr * PL + kb * 64 + sg * 8, &Vs[(wave * 16) * 64]);
        gl2lds16(Vt + kvbase + (size_t)(sr + 8) * PL + kb * 64 + sg * 8, &Vs[(wave * 16 + 8) * 64]);
        __syncthreads();

        // ---- phase 1: S^T - M for both q-groups (kA live) ----
        s16x8 kA[4][2];
#pragma unroll
        for (int s = 0; s < 4; s++) {
            kA[s][0] = *(const s16x8*)&Ks[(s * 16 + rr) * 64 + ((0 + quad) ^ swz8) * 8];
            kA[s][1] = *(const s16x8*)&Ks[(s * 16 + rr) * 64 + ((4 + quad) ^ swz8) * 8];
        }
        f32x4 sc4[2][4];
#pragma unroll
        for (int g = 0; g < 2; g++)
#pragma unroll
            for (int s = 0; s < 4; s++) {
                f32x4 z = MFMA16(kA[s][0], qB[g][0], negM);
                z = MFMA16(kA[s][1], qB[g][1], z);
                sc4[g][s] = z;
            }

        // optional bias (uniform branch; skipped when attn_bias == 0)
        if (hasbias) {
#pragma unroll
            for (int g = 0; g < 2; g++) {
                const float* brow = bias + (size_t)(q0 + g * 64 + wave * 16 + rr) * PL + kb * 64;
#pragma unroll
                for (int s = 0; s < 4; s++) {
                    float4 bv = *(const float4*)(brow + s * 16 + quad * 4);
                    sc4[g][s][0] = fmaf(bv.x, LOG2E, sc4[g][s][0]);
                    sc4[g][s][1] = fmaf(bv.y, LOG2E, sc4[g][s][1]);
                    sc4[g][s][2] = fmaf(bv.z, LOG2E, sc4[g][s][2]);
                    sc4[g][s][3] = fmaf(bv.w, LOG2E, sc4[g][s][3]);
                }
            }
        }

        // ---- softmax: p = exp2(s - M) ----
#pragma unroll
        for (int g = 0; g < 2; g++)
#pragma unroll
            for (int s = 0; s < 4; s++) {
                sc4[g][s][0] = EXP2(sc4[g][s][0]);
                sc4[g][s][1] = EXP2(sc4[g][s][1]);
                sc4[g][s][2] = EXP2(sc4[g][s][2]);
                sc4[g][s][3] = EXP2(sc4[g][s][3]);
                lsum[g] += sc4[g][s][0] + sc4[g][s][1] + sc4[g][s][2] + sc4[g][s][3];
            }

        // ---- phase 2: PV for both q-groups (vA live; Ps reused per group) ----
        s16x8 vA[4][2];
#pragma unroll
        for (int s = 0; s < 4; s++) {
            vA[s][0] = *(const s16x8*)&Vs[(s * 16 + rr) * 64 + ((0 + quad) ^ swz8) * 8];
            vA[s][1] = *(const s16x8*)&Vs[(s * 16 + rr) * 64 + ((4 + quad) ^ swz8) * 8];
        }
#pragma unroll
        for (int g = 0; g < 2; g++) {
#pragma unroll
            for (int s = 0; s < 4; s++) {
                *(uint2*)&Ps[wave][rr * 36 + s * 8 + quad * 2] =
                    make_uint2(pk2bf(sc4[g][s][0], sc4[g][s][1]),
                               pk2bf(sc4[g][s][2], sc4[g][s][3]));
            }
            // same-wave LDS ops are in-order: no barrier needed
            s16x8 pB0 = *(const s16x8*)&Ps[wave][rr * 36 + quad * 4];
            s16x8 pB1 = *(const s16x8*)&Ps[wave][rr * 36 + 16 + quad * 4];
#pragma unroll
            for (int jd = 0; jd < 4; jd++) {
                accO[g][jd] = MFMA16(vA[jd][0], pB0, accO[g][jd]);
                accO[g][jd] = MFMA16(vA[jd][1], pB1, accO[g][jd]);
            }
        }
        __syncthreads();
    }

    // final l reduction across quads; epilogue via per-wave LDS transpose
    const int lr = lane >> 2, cch = lane & 3;
#pragma unroll
    for (int g = 0; g < 2; g++) {
        float ls = lsum[g];
        ls += __shfl_xor(ls, 16);
        ls += __shfl_xor(ls, 32);
        float inv = 1.0f / ls;
#pragma unroll
        for (int jd = 0; jd < 4; jd++) {
            *(uint2*)&Ps[wave][rr * 36 + jd * 8 + quad * 2] =
                make_uint2(pk2bf(accO[g][jd][0] * inv, accO[g][jd][1] * inv),
                           pk2bf(accO[g][jd][2] * inv, accO[g][jd][3] * inv));
        }
        uint4 w0 = *(const uint4*)&Ps[wave][lr * 36 + cch * 8];
        uint4 w1 = *(const uint4*)&Ps[wave][lr * 36 + cch * 8 + 4];
        size_t ob = ((size_t)(b * PL + q0 + g * 64 + wave * 16 + lr) * PC + h * PD);
        *(uint4*)(O + ob + cch * 16)     = w0;
        *(uint4*)(O + ob + cch * 16 + 8) = w1;
    }
}

// ---------------------------------------------------------------------------
// Kernel 4: out-proj GEMM, transposed compute Out^T-style (n in reg), BK=64.
// Out = Oh(8192x1024) . Wph(1024x1024)^T + bp, fp32 out, float4 stores.
// ---------------------------------------------------------------------------
__global__ __launch_bounds__(256) void gemm_proj_mfma(
    const unsigned short* __restrict__ Ah,
    const unsigned short* __restrict__ Wh,
    const float* __restrict__ bp, float* __restrict__ Out)
{
    __shared__ unsigned short As[128 * 64];
    __shared__ unsigned short Bs[128 * 64];
    const int tid  = threadIdx.x;
    const int wave = tid >> 6, lane = tid & 63;
    const int wm = wave & 1, wn = wave >> 1;
    const int quad = lane >> 4, rr = lane & 15;
    const int m0 = blockIdx.x * 128, n0 = blockIdx.y * 128;

    f32x4 acc[4][4];   // i over n sub-tiles, j over m sub-tiles
#pragma unroll
    for (int i = 0; i < 4; i++)
#pragma unroll
        for (int j = 0; j < 4; j++) acc[i][j] = (f32x4){0.f, 0.f, 0.f, 0.f};

    const int r8 = lane >> 3;
    const int c8 = lane & 7;
    const int g  = c8 ^ r8;
    const unsigned short* gA = Ah + (size_t)(m0 + wave * 32 + r8) * 1024 + g * 8;
    const unsigned short* gB = Wh + (size_t)(n0 + wave * 32 + r8) * 1024 + g * 8;
    unsigned short* lA = &As[(wave * 32) * 64];
    unsigned short* lB = &Bs[(wave * 32) * 64];

    const int swz8 = rr & 7;

    for (int k0 = 0; k0 < 16; k0++) {
#pragma unroll
        for (int t = 0; t < 4; t++) {
            gl2lds16(gA + (size_t)t * 8192, &lA[(t * 8) * 64]);
            gl2lds16(gB + (size_t)t * 8192, &lB[(t * 8) * 64]);
        }
        gA += 64; gB += 64;
        __syncthreads();

#pragma unroll
        for (int kk = 0; kk < 2; kk++) {
            const int coff = ((kk * 4 + quad) ^ swz8) * 8;
            s16x8 wf[4], xf[4];
#pragma unroll
            for (int i = 0; i < 4; i++)
                wf[i] = *(const s16x8*)&Bs[(wn * 64 + i * 16 + rr) * 64 + coff];
#pragma unroll
            for (int j = 0; j < 4; j++)
                xf[j] = *(const s16x8*)&As[(wm * 64 + j * 16 + rr) * 64 + coff];
#pragma unroll
            for (int i = 0; i < 4; i++)
#pragma unroll
                for (int j = 0; j < 4; j++)
                    acc[i][j] = MFMA16(wf[i], xf[j], acc[i][j]);
        }
        __syncthreads();
    }

    // epilogue: n = n0 + wn*64 + i*16 + quad*4 (+reg), m = m0 + wm*64 + j*16 + rr
#pragma unroll
    for (int i = 0; i < 4; i++) {
        const int nn = n0 + wn * 64 + i * 16 + quad * 4;
        const float4 bb = *(const float4*)(bp + nn);
#pragma unroll
        for (int j = 0; j < 4; j++) {
            const int m = m0 + wm * 64 + j * 16 + rr;
            float4 o = make_float4(acc[i][j][0] + bb.x, acc[i][j][1] + bb.y,
                                   acc[i][j][2] + bb.z, acc[i][j][3] + bb.w);
            *(float4*)(Out + (size_t)m * 1024 + nn) = o;
        }
    }
}

// ---------------------------------------------------------------------------
extern "C" void kernel_launch(void* const* d_in, const int* in_sizes, int n_in,
                              void* d_out, int out_size, void* d_ws, size_t ws_size,
                              hipStream_t stream)
{
    const float* x         = (const float*)d_in[0];
    const float* freqs     = (const float*)d_in[1];
    const float* attn_bias = (const float*)d_in[2];
    const float* W_qkv     = (const float*)d_in[3];
    const float* q_bias    = (const float*)d_in[4];
    const float* v_bias    = (const float*)d_in[5];
    const float* sml       = (const float*)d_in[6];
    const float* W_proj    = (const float*)d_in[7];
    const float* b_proj    = (const float*)d_in[8];
    float* out = (float*)d_out;

    unsigned char* w = (unsigned char*)d_ws;
    const size_t MB = 1ull << 20;
    unsigned short* xh  = (unsigned short*)(w + 0);        // 16 MiB
    unsigned short* wqh = (unsigned short*)(w + 16 * MB);  //  6 MiB
    unsigned short* wph = (unsigned short*)(w + 22 * MB);  //  2 MiB
    unsigned short* Qh  = (unsigned short*)(w + 24 * MB);  // 16 MiB (raw Q+bias)
    unsigned short* Kh  = (unsigned short*)(w + 40 * MB);  // 16 MiB (in-place norm+rope)
    unsigned short* Vh  = (unsigned short*)(w + 56 * MB);  // 16 MiB raw V (B,H,L,D)
    unsigned short* Vt  = (unsigned short*)(w + 72 * MB);  // 16 MiB (B,H,D,L)
    unsigned short* Oh  = (unsigned short*)(w + 88 * MB);  // 16 MiB (B,L,H,D)
    int*            flg = (int*)(w + 104 * MB);            //  4 B bias flag

    // 0. zero bias flag (ws is poisoned 0xAA)
    hipMemsetAsync(flg, 0, sizeof(int), stream);
    // 1. fused casts + bias scan
    cast3f_kernel<<<12544, 256, 0, stream>>>(x, W_qkv, W_proj, attn_bias,
                                             xh, wqh, wph, flg);
    // 2. QKV projection (BK=64)
    gemm_qkv_lean<<<dim3(64, 24), 256, 0, stream>>>(xh, wqh, q_bias, v_bias, Qh, Kh, Vh);
    // 3. postprocess: K norm+RoPE in place, V transpose
    postproc_kernel<<<18432, 256, 0, stream>>>(Kh, Vh, Vt, freqs);
    // 4. flash attention (in-register Q norm+RoPE)
    attn_mfma<<<dim3(128, 8), 256, 0, stream>>>(Qh, Kh, Vt, attn_bias, sml, flg, freqs, Oh);
    // 5. output projection (BK=64, transposed epilogue)
    gemm_proj_mfma<<<dim3(64, 8), 256, 0, stream>>>(Oh, wph, b_proj, out);
}